// Round 15
// baseline (508.455 us; speedup 1.0000x reference)
//
#include <hip/hip_runtime.h>
#include <hip/hip_bf16.h>

namespace {

constexpr int NN = 30000;   // nodes
constexpr int NE = 60000;   // edges
constexpr int NB = 1200;    // graphs
constexpr int MD = 64;      // DIM
constexpr int FE = 14;      // FEAT
constexpr int PG = 25;      // nodes per graph
constexpr int KH = 128;     // edge-MLP hidden width

typedef __attribute__((ext_vector_type(8))) __bf16 bf16x8;
typedef __attribute__((ext_vector_type(4))) float f32x4;

__device__ __forceinline__ float sigf(float x) { return 1.0f / (1.0f + expf(-x)); }
__device__ __forceinline__ float dot4(f32x4 a, f32x4 b) {
  return a[0]*b[0] + a[1]*b[1] + a[2]*b[2] + a[3]*b[3];
}
__device__ __forceinline__ unsigned short f2bf(float f) {
  __hip_bfloat16 h = __float2bfloat16(f);
  return *reinterpret_cast<unsigned short*>(&h);
}

// ---------------- lin0: node_h = relu(x @ W_lin0.T + b) ----------------
__global__ __launch_bounds__(256) void k_lin0(const float* __restrict__ x,
    const float* __restrict__ W, const float* __restrict__ b,
    float* __restrict__ node_h)
{
  __shared__ float xs[4][FE];
  int tid = threadIdx.x, nl = tid >> 6, d = tid & 63;
  int n = blockIdx.x * 4 + nl;
  if (d < FE) xs[nl][d] = x[n * FE + d];
  __syncthreads();
  float a = b[d];
#pragma unroll
  for (int f = 0; f < FE; ++f) a += xs[nl][f] * W[d * FE + f];
  node_h[n * MD + d] = fmaxf(a, 0.0f);
}

// ------------- h1 = relu(edge_attr @ W_h1.T + b) -> bf16, 16 outputs/thread -------------
__global__ __launch_bounds__(256) void k_h1(const float* __restrict__ ea,
    const float* __restrict__ W, const float* __restrict__ b,
    __hip_bfloat16* __restrict__ h1)
{
  int t = blockIdx.x * 256 + threadIdx.x;   // < NE*8 = 480000
  int e = t >> 3, kg = t & 7;
  f32x4 a = *reinterpret_cast<const f32x4*>(ea + e * 4);
  uint ww[8];
#pragma unroll
  for (int p = 0; p < 8; ++p) {
    int k = kg * 16 + p * 2;
    float v0 = b[k]     + dot4(a, *reinterpret_cast<const f32x4*>(W + k * 4));
    float v1 = b[k + 1] + dot4(a, *reinterpret_cast<const f32x4*>(W + (k + 1) * 4));
    ww[p] = (uint)f2bf(fmaxf(v0, 0.f)) | ((uint)f2bf(fmaxf(v1, 0.f)) << 16);
  }
  uint4* dst = reinterpret_cast<uint4*>(h1 + (size_t)e * KH + kg * 16);
  uint4 u0; u0.x = ww[0]; u0.y = ww[1]; u0.z = ww[2]; u0.w = ww[3];
  uint4 u1; u1.x = ww[4]; u1.y = ww[5]; u1.z = ww[6]; u1.w = ww[7];
  dst[0] = u0; dst[1] = u1;
}

// ---------------- degree ----------------
__global__ __launch_bounds__(256) void k_deg(const int* __restrict__ tgt, int* __restrict__ cnt)
{
  int e = blockIdx.x * 256 + threadIdx.x;
  if (e < NE) atomicAdd(&cnt[tgt[e]], 1);
}

// ------------- ONE pack kernel: bpre | WG | PH1 | Lih | Lhh | L1p | inv_deg -------------
// bpre: MFMA B-frag order. WG: [j/4][6][64][4]. PH1: [i/4][2][64][4] (b_h2 | W_root).
// Lih: [j/4][4][64][4]. Lhh: [j/4][4][64][4]. L1p: [j/4][64][4].
__global__ __launch_bounds__(256) void k_pack(const float* __restrict__ W_h2,
    const float* __restrict__ W_ih, const float* __restrict__ W_hh,
    const float* __restrict__ b_h2, const float* __restrict__ W_root,
    const float* __restrict__ W_lih, const float* __restrict__ W_lhh,
    const float* __restrict__ W_lin1, const int* __restrict__ cnt,
    __hip_bfloat16* __restrict__ bpre, float* __restrict__ WG,
    float* __restrict__ PH1, float* __restrict__ Lih, float* __restrict__ Lhh,
    float* __restrict__ L1p, float* __restrict__ inv)
{
  int t = blockIdx.x * 256 + threadIdx.x;
  if (t < 524288) {
    int j = t & 7, l = (t >> 3) & 63, ot = (t >> 9) & 3, ks = (t >> 11) & 3, i = t >> 13;
    int row = i * MD + ot * 16 + (l & 15);
    int col = ks * 32 + (l >> 4) * 8 + j;
    bpre[t] = __float2bfloat16(W_h2[row * KH + col]);
  } else if ((t -= 524288) < 24576) {
    int jb = t / 1536, r = t % 1536;
    int g = r >> 8, r2 = r & 255, d = r2 >> 2, j = jb * 4 + (r2 & 3);
    WG[t] = (g < 3) ? W_ih[(g * 64 + d) * 64 + j] : W_hh[((g - 3) * 64 + d) * 64 + j];
  } else if ((t -= 24576) < 8192) {
    int ib = t >> 9, r = t & 511;
    int which = r >> 8, r2 = r & 255, d = r2 >> 2, i = ib * 4 + (r2 & 3);
    PH1[t] = which ? W_root[i * 64 + d] : b_h2[i * 64 + d];
  } else if ((t -= 8192) < 32768) {
    int jb = t >> 10, r = t & 1023;
    int g = r >> 8, r2 = r & 255, d = r2 >> 2, j = jb * 4 + (r2 & 3);
    Lih[t] = W_lih[(g * 64 + d) * 128 + j];
  } else if ((t -= 32768) < 16384) {
    int jb = t >> 10, r = t & 1023;
    int g = r >> 8, r2 = r & 255, d = r2 >> 2, j = jb * 4 + (r2 & 3);
    Lhh[t] = W_lhh[(g * 64 + d) * 64 + j];
  } else if ((t -= 16384) < 8192) {
    int jb = t >> 8, r = t & 255, d = r >> 2, j = jb * 4 + (r & 3);
    L1p[t] = W_lin1[d * 128 + j];
  } else if ((t -= 8192) < NN) {
    inv[t] = 1.0f / fmaxf((float)cnt[t], 1.0f);
  }
}

// ------------- message kernel: 128 edges/block, 4 waves x 32 edges, i-split x2 ---------
// Partial C[e,o] = sum_{i in [32yi,32yi+32)} x[src_e,i]*(h1_e.W2[i*64+o,:]) -> atomic aggr.
// i processed in PAIRS: stage holds 32 fragments (two i's), 16 iterations with ONE
// barrier-pair each (vs R12's 32) -- halves the fixed per-iteration latency cost that
// R12/R14 showed to be the binding term (both 90us at very different LDS/occupancy mixes).
__global__ __launch_bounds__(256, 3) void k_msg(
    const __hip_bfloat16* __restrict__ h1,
    const __hip_bfloat16* __restrict__ bpre,
    const float* __restrict__ node_h,
    const int* __restrict__ src,
    const int* __restrict__ tgt,
    float* __restrict__ sx,
    float* __restrict__ aggr)
{
  __shared__ float xT[32 * 132];     // [i-i0][edge], stride 132 (16B-aligned rows)
  __shared__ bf16x8 stage[2048];     // 32KB: 2 i-values x 16 fragments x 64 lanes
  __shared__ int s_src[128];
  __shared__ int s_tgt[128];
  const int tid = threadIdx.x;       // 0..255
  const int wid = tid >> 6;          // 0..3
  const int lane = tid & 63;
  const int eb0 = blockIdx.x * 128;
  const int i0 = blockIdx.y * 32;

  if (tid < 128) {
    int ge = eb0 + tid;
    bool v = ge < NE;
    s_src[tid] = v ? src[ge] : -1;
    s_tgt[tid] = v ? tgt[ge] : -1;
  }
  __syncthreads();
  // stage xT (transposed, this i-range) + fused partial segment-sum of x_src
#pragma unroll 4
  for (int k = 0; k < 16; ++k) {
    int idx = k * 256 + tid;          // < 4096 = 128 edges * 32 dims
    int el = idx >> 5, dd = idx & 31;
    int s = s_src[el];
    float v = (s >= 0) ? node_h[s * MD + i0 + dd] : 0.0f;
    xT[dd * 132 + el] = v;
    if (s >= 0) atomicAdd(&sx[s_tgt[el] * MD + i0 + dd], v);
  }

  // A fragments: h1 rows (edges). lane: row = lane&15, k = ks*32 + (lane>>4)*8 + j
  const int ew = wid * 32;
  bf16x8 af[2][4];
#pragma unroll
  for (int m = 0; m < 2; ++m) {
    int ge = eb0 + ew + m * 16 + (lane & 15);
    if (ge >= NE) ge = 0;                      // xT row is 0 for OOB -> contribution = 0
    const bf16x8* ap = reinterpret_cast<const bf16x8*>(h1 + (size_t)ge * KH);
#pragma unroll
    for (int ks = 0; ks < 4; ++ks)
      af[m][ks] = ap[ks * 4 + (lane >> 4)];
  }

  // prologue: stage fragments for pair 0 (i0, i0+1); wave wid owns frags 4*wid..4*wid+3
  const bf16x8* bpre8 = reinterpret_cast<const bf16x8*>(bpre);
  const int fb = wid << 2;
  {
    bf16x8 r0[8];
#pragma unroll
    for (int q = 0; q < 8; ++q) {
      int p = q >> 2, f = fb + (q & 3);
      r0[q] = bpre8[((((i0 + p) * 16) + f) << 6) + lane];
    }
#pragma unroll
    for (int q = 0; q < 8; ++q) {
      int p = q >> 2, f = fb + (q & 3);
      stage[(p << 10) + (f << 6) + lane] = r0[q];
    }
  }
  __syncthreads();   // xT + stage ready

  const f32x4 z4 = {0.0f, 0.0f, 0.0f, 0.0f};
  f32x4 c[2][4];
#pragma unroll
  for (int m = 0; m < 2; ++m)
#pragma unroll
    for (int ot = 0; ot < 4; ++ot) c[m][ot] = z4;

  for (int i2 = 0; i2 < 16; ++i2) {
    // issue next pair's fragment loads early (in flight across the read phase)
    bf16x8 rn[8];
    if (i2 < 15) {
#pragma unroll
      for (int q = 0; q < 8; ++q) {
        int p = q >> 2, f = fb + (q & 3);
        rn[q] = bpre8[((((i0 + (i2 + 1) * 2 + p) * 16) + f) << 6) + lane];
      }
    }
    // compute both i's of the pair from stage
#pragma unroll
    for (int p = 0; p < 2; ++p) {
      const int ii = i2 * 2 + p;
      f32x4 g[2][4];
#pragma unroll
      for (int ks = 0; ks < 4; ++ks) {
        bf16x8 bfr[4];
#pragma unroll
        for (int ot = 0; ot < 4; ++ot)
          bfr[ot] = stage[(p << 10) + (((ks * 4 + ot)) << 6) + lane];
#pragma unroll
        for (int ot = 0; ot < 4; ++ot)
#pragma unroll
          for (int m = 0; m < 2; ++m)
            g[m][ot] = __builtin_amdgcn_mfma_f32_16x16x32_bf16(
                af[m][ks], bfr[ot], (ks == 0) ? z4 : g[m][ot], 0, 0, 0);
      }
#pragma unroll
      for (int m = 0; m < 2; ++m) {
        f32x4 xv = *reinterpret_cast<const f32x4*>(
            &xT[ii * 132 + ew + m * 16 + ((lane >> 4) << 2)]);
#pragma unroll
        for (int ot = 0; ot < 4; ++ot)
          c[m][ot] += xv * g[m][ot];
      }
    }
    __syncthreads();   // all waves done READING stage for this pair
    if (i2 < 15) {
#pragma unroll
      for (int q = 0; q < 8; ++q) {
        int p = q >> 2, f = fb + (q & 3);
        stage[(p << 10) + (f << 6) + lane] = rn[q];
      }
    }
    __syncthreads();   // stage holds next pair
  }

  // scatter partial C into aggr[tgt]  (C/D layout: col=lane&15, row=(lane>>4)*4+r)
#pragma unroll
  for (int m = 0; m < 2; ++m)
#pragma unroll
    for (int r = 0; r < 4; ++r) {
      int el = ew + m * 16 + (lane >> 4) * 4 + r;
      int t = s_tgt[el];
      if (t >= 0) {
#pragma unroll
        for (int ot = 0; ot < 4; ++ot)
          atomicAdd(&aggr[t * MD + ot * 16 + (lane & 15)], c[m][ot][r]);
      }
    }
}

// ------------- NNConv epilogue + GRU: 16 nodes/block, 2 waves, 8 nodes/thread -------------
// (R10-R14-proven). Per-thread inner code identical to the R4/R6 shape; 128-thread
// blocks double the grid (1875 blocks, ~7.3/CU) and halve LDS (12KB).
__global__ __launch_bounds__(128) void k_gru(
    float* __restrict__ node_h,
    const float* __restrict__ aggr, const float* __restrict__ sx,
    const float* __restrict__ inv_deg,
    const f32x4* __restrict__ WG,      // [j/4][6][64] f32x4
    const f32x4* __restrict__ PH1,     // [i/4][2][64] f32x4
    const float* __restrict__ b_conv,
    const float* __restrict__ b_ih, const float* __restrict__ b_hh)
{
  __shared__ float h_s[16][64], sx_s[16][64], m_s[16][64];
  const f32x4 z4 = {0.f, 0.f, 0.f, 0.f};
  int tid = threadIdx.x, w = tid >> 6, d = tid & 63;
  int n0 = blockIdx.x * 16;
  {
    const f32x4* hp = reinterpret_cast<const f32x4*>(node_h + (size_t)n0 * MD);
    const f32x4* sp = reinterpret_cast<const f32x4*>(sx + (size_t)n0 * MD);
    f32x4* hs4 = reinterpret_cast<f32x4*>(&h_s[0][0]);
    f32x4* ss4 = reinterpret_cast<f32x4*>(&sx_s[0][0]);
#pragma unroll
    for (int k = tid; k < 256; k += 128) {
      bool ok = (n0 + (k >> 4)) < NN;
      hs4[k] = ok ? hp[k] : z4;
      ss4[k] = ok ? sp[k] : z4;
    }
  }
  __syncthreads();
  const int gb = w * 8;                       // this wave's first node (block-local)
  float acc[8], mr[8];
#pragma unroll
  for (int g = 0; g < 8; ++g) {
    int n = n0 + gb + g;
    acc[g] = (n < NN) ? aggr[n * MD + d] : 0.f;
    mr[g] = 0.f;
  }
  for (int ib = 0; ib < 16; ++ib) {
    f32x4 wsx = PH1[ib * 128 + d];
    f32x4 wrt = PH1[ib * 128 + 64 + d];
#pragma unroll
    for (int g = 0; g < 8; ++g) {
      f32x4 s4 = *reinterpret_cast<const f32x4*>(&sx_s[gb + g][ib * 4]);
      f32x4 h4 = *reinterpret_cast<const f32x4*>(&h_s[gb + g][ib * 4]);
      acc[g] += dot4(s4, wsx);
      mr[g]  += dot4(h4, wrt);
    }
  }
  float bc = b_conv[d];
#pragma unroll
  for (int g = 0; g < 8; ++g) {
    int n = n0 + gb + g;
    float iv = (n < NN) ? inv_deg[n] : 1.f;
    m_s[gb + g][d] = fmaxf(acc[g] * iv + mr[g] + bc, 0.f);
  }
  // m_s is wave-local (written and read by the same wave) - no barrier needed
  float gir[8], giz[8], gin[8], ghr[8], ghz[8], ghn[8];
  float bi0 = b_ih[d], bi1 = b_ih[64 + d], bi2 = b_ih[128 + d];
  float bh0 = b_hh[d], bh1 = b_hh[64 + d], bh2 = b_hh[128 + d];
#pragma unroll
  for (int g = 0; g < 8; ++g) {
    gir[g] = bi0; giz[g] = bi1; gin[g] = bi2;
    ghr[g] = bh0; ghz[g] = bh1; ghn[g] = bh2;
  }
  for (int jb = 0; jb < 16; ++jb) {
    f32x4 w0 = WG[jb * 384 + d];
    f32x4 w1 = WG[jb * 384 + 64 + d];
    f32x4 w2 = WG[jb * 384 + 128 + d];
    f32x4 w3 = WG[jb * 384 + 192 + d];
    f32x4 w4 = WG[jb * 384 + 256 + d];
    f32x4 w5 = WG[jb * 384 + 320 + d];
#pragma unroll
    for (int g = 0; g < 8; ++g) {
      f32x4 m4 = *reinterpret_cast<const f32x4*>(&m_s[gb + g][jb * 4]);
      f32x4 h4 = *reinterpret_cast<const f32x4*>(&h_s[gb + g][jb * 4]);
      gir[g] += dot4(m4, w0); giz[g] += dot4(m4, w1); gin[g] += dot4(m4, w2);
      ghr[g] += dot4(h4, w3); ghz[g] += dot4(h4, w4); ghn[g] += dot4(h4, w5);
    }
  }
#pragma unroll
  for (int g = 0; g < 8; ++g) {
    int n = n0 + gb + g;
    if (n < NN) {
      float hv = h_s[gb + g][d];
      float r = sigf(gir[g] + ghr[g]), z = sigf(giz[g] + ghz[g]);
      float nv = tanhf(gin[g] + r * ghn[g]);
      node_h[n * MD + d] = (1.f - z) * nv + z * hv;
    }
  }
}

// ------------- fused Set2Set (3 iters) + head: 256 threads, ONE graph per block ----------
// (R12-proven: gate-row-parallel GEMV + unroll-8 latency batching; state in LDS.)
__global__ __launch_bounds__(256) void k_s2s(const float* __restrict__ node_h,
    const f32x4* __restrict__ Lih, const f32x4* __restrict__ Lhh,
    const float* __restrict__ b_lih, const float* __restrict__ b_lhh,
    const f32x4* __restrict__ L1p, const float* __restrict__ b_lin1,
    const float* __restrict__ W_lin2, const float* __restrict__ b_lin2,
    float* __restrict__ out)
{
  __shared__ __align__(16) float qs[128];   // q_star = [q | rvec]
  __shared__ __align__(16) float hs[64];
  __shared__ float cls[64];
  __shared__ float ga[256];
  __shared__ float ev[32];
  const int tid = threadIdx.x;
  const int b = blockIdx.x;
  const float* nb = node_h + (size_t)b * PG * MD;

  if (tid < 128) {
    qs[tid] = 0.f;
    if (tid < 64) { hs[tid] = 0.f; cls[tid] = 0.f; }
    qs[64 + (tid & 63)] = 0.f;
  }
  __syncthreads();

  for (int it = 0; it < 3; ++it) {
    // ---- gates: thread t = gate row t (i,f,g,o x 64) ----
    float a0 = b_lih[tid] + b_lhh[tid];
    const f32x4* q4 = reinterpret_cast<const f32x4*>(qs);
#pragma unroll 8
    for (int jb = 0; jb < 32; ++jb)
      a0 += dot4(q4[jb], Lih[jb * 256 + tid]);
    const f32x4* h4 = reinterpret_cast<const f32x4*>(hs);
#pragma unroll 8
    for (int jb = 0; jb < 16; ++jb)
      a0 += dot4(h4[jb], Lhh[jb * 256 + tid]);
    ga[tid] = a0;
    __syncthreads();
    // ---- LSTM pointwise (threads 0..63) ----
    if (tid < 64) {
      float ai = ga[tid], af_ = ga[64 + tid], ag = ga[128 + tid], ao = ga[192 + tid];
      float c = sigf(af_) * cls[tid] + sigf(ai) * tanhf(ag);
      float h = sigf(ao) * tanhf(c);
      cls[tid] = c; hs[tid] = h; qs[tid] = h;
    }
    __syncthreads();
    // ---- attention scores: wave wv handles nodes n = wv, wv+4, ... ----
    {
      int wv = tid >> 6, lane = tid & 63;
      float hv = hs[lane];
      for (int n = wv; n < PG; n += 4) {
        float v = nb[n * MD + lane] * hv;
#pragma unroll
        for (int m = 32; m >= 1; m >>= 1) v += __shfl_xor(v, m, 64);
        if (lane == 0) ev[n] = v;
      }
    }
    __syncthreads();
    // ---- softmax + rvec (threads 0..63; ev reads are LDS broadcasts) ----
    if (tid < 64) {
      float emax = -3.0e38f;
#pragma unroll
      for (int n = 0; n < PG; ++n) emax = fmaxf(emax, ev[n]);
      float s = 0.f, rv = 0.f;
#pragma unroll
      for (int n = 0; n < PG; ++n) {
        float w_ = expf(ev[n] - emax);
        s += w_;
        rv += w_ * nb[n * MD + tid];
      }
      qs[64 + tid] = rv / s;
    }
    __syncthreads();
  }
  // ---- head (threads 0..63) ----
  if (tid < 64) {
    const f32x4* q4 = reinterpret_cast<const f32x4*>(qs);
    float aa = b_lin1[tid];
#pragma unroll 8
    for (int jb = 0; jb < 32; ++jb) aa += dot4(q4[jb], L1p[jb * 64 + tid]);
    aa = fmaxf(aa, 0.f);
    float v = aa * W_lin2[tid];
#pragma unroll
    for (int m = 32; m >= 1; m >>= 1) v += __shfl_xor(v, m, 64);
    if (tid == 0) out[b] = v + b_lin2[0];
  }
}

} // namespace

extern "C" void kernel_launch(void* const* d_in, const int* in_sizes, int n_in,
                              void* d_out, int out_size, void* d_ws, size_t ws_size,
                              hipStream_t stream)
{
  const float* x      = (const float*)d_in[0];
  const float* ea     = (const float*)d_in[1];
  const float* W_lin0 = (const float*)d_in[2];
  const float* b_lin0 = (const float*)d_in[3];
  const float* W_h1   = (const float*)d_in[4];
  const float* b_h1   = (const float*)d_in[5];
  const float* W_h2   = (const float*)d_in[6];
  const float* b_h2   = (const float*)d_in[7];
  const float* W_root = (const float*)d_in[8];
  const float* b_conv = (const float*)d_in[9];
  const float* W_ih   = (const float*)d_in[10];
  const float* W_hh   = (const float*)d_in[11];
  const float* b_ih   = (const float*)d_in[12];
  const float* b_hh   = (const float*)d_in[13];
  const float* W_lih  = (const float*)d_in[14];
  const float* W_lhh  = (const float*)d_in[15];
  const float* b_lih  = (const float*)d_in[16];
  const float* b_lhh  = (const float*)d_in[17];
  const float* W_lin1 = (const float*)d_in[18];
  const float* b_lin1 = (const float*)d_in[19];
  const float* W_lin2 = (const float*)d_in[20];
  const float* b_lin2 = (const float*)d_in[21];
  const int*   eidx   = (const int*)d_in[22];
  const int* src = eidx;
  const int* tgt = eidx + NE;
  float* out = (float*)d_out;
  (void)in_sizes; (void)n_in; (void)out_size; (void)ws_size;

  // ---- workspace carve-up (~40 MB) ----
  char* w = (char*)d_ws;
  size_t off = 0;
  auto take = [&](size_t bytes) -> void* {
    void* p = w + off;
    off += (bytes + 255) & ~(size_t)255;
    return p;
  };
  float* node_h        = (float*)take((size_t)NN * MD * 4);
  __hip_bfloat16* h1   = (__hip_bfloat16*)take((size_t)NE * KH * 2);
  __hip_bfloat16* bpre = (__hip_bfloat16*)take((size_t)524288 * 2);
  float* aggr          = (float*)take((size_t)NN * MD * 4);  // aggr, sx contiguous
  float* sx            = (float*)take((size_t)NN * MD * 4);
  float* inv_deg       = (float*)take((size_t)NN * 4);
  int*   deg_cnt       = (int*)take((size_t)NN * 4);
  float* WG            = (float*)take((size_t)24576 * 4);
  float* PH1           = (float*)take((size_t)8192 * 4);
  float* Lih           = (float*)take((size_t)32768 * 4);
  float* Lhh           = (float*)take((size_t)16384 * 4);
  float* L1p           = (float*)take((size_t)8192 * 4);

  hipMemsetAsync(deg_cnt, 0, (size_t)NN * 4, stream);
  k_deg<<<(NE + 255) / 256, 256, 0, stream>>>(tgt, deg_cnt);
  k_pack<<<2518, 256, 0, stream>>>(W_h2, W_ih, W_hh, b_h2, W_root, W_lih, W_lhh,
                                   W_lin1, deg_cnt, bpre, WG, PH1, Lih, Lhh, L1p,
                                   inv_deg);
  k_lin0<<<NN / 4, 256, 0, stream>>>(x, W_lin0, b_lin0, node_h);
  k_h1<<<(NE * 8) / 256, 256, 0, stream>>>(ea, W_h1, b_h1, h1);

  dim3 msg_grid((NE + 127) / 128, 2);
  for (int step = 0; step < 3; ++step) {
    hipMemsetAsync(aggr, 0, (size_t)NN * MD * 4 * 2, stream);   // aggr + sx
    k_msg<<<msg_grid, 256, 0, stream>>>(h1, bpre, node_h, src, tgt, sx, aggr);
    k_gru<<<(NN + 15) / 16, 128, 0, stream>>>(node_h, aggr, sx, inv_deg,
                                              (const f32x4*)WG, (const f32x4*)PH1,
                                              b_conv, b_ih, b_hh);
  }

  k_s2s<<<NB, 256, 0, stream>>>(node_h, (const f32x4*)Lih, (const f32x4*)Lhh,
                                b_lih, b_lhh, (const f32x4*)L1p, b_lin1,
                                W_lin2, b_lin2, out);
}

// Round 16
// 498.325 us; speedup vs baseline: 1.0203x; 1.0203x over previous
//
#include <hip/hip_runtime.h>
#include <hip/hip_bf16.h>

namespace {

constexpr int NN = 30000;   // nodes
constexpr int NE = 60000;   // edges
constexpr int NB = 1200;    // graphs
constexpr int MD = 64;      // DIM
constexpr int FE = 14;      // FEAT
constexpr int PG = 25;      // nodes per graph
constexpr int KH = 128;     // edge-MLP hidden width

typedef __attribute__((ext_vector_type(8))) __bf16 bf16x8;
typedef __attribute__((ext_vector_type(4))) float f32x4;

__device__ __forceinline__ float sigf(float x) { return 1.0f / (1.0f + expf(-x)); }
__device__ __forceinline__ float dot4(f32x4 a, f32x4 b) {
  return a[0]*b[0] + a[1]*b[1] + a[2]*b[2] + a[3]*b[3];
}
__device__ __forceinline__ unsigned short f2bf(float f) {
  __hip_bfloat16 h = __float2bfloat16(f);
  return *reinterpret_cast<unsigned short*>(&h);
}

// ---------------- lin0: node_h = relu(x @ W_lin0.T + b) ----------------
__global__ __launch_bounds__(256) void k_lin0(const float* __restrict__ x,
    const float* __restrict__ W, const float* __restrict__ b,
    float* __restrict__ node_h)
{
  __shared__ float xs[4][FE];
  int tid = threadIdx.x, nl = tid >> 6, d = tid & 63;
  int n = blockIdx.x * 4 + nl;
  if (d < FE) xs[nl][d] = x[n * FE + d];
  __syncthreads();
  float a = b[d];
#pragma unroll
  for (int f = 0; f < FE; ++f) a += xs[nl][f] * W[d * FE + f];
  node_h[n * MD + d] = fmaxf(a, 0.0f);
}

// ------------- h1 = relu(edge_attr @ W_h1.T + b) -> bf16, 16 outputs/thread -------------
__global__ __launch_bounds__(256) void k_h1(const float* __restrict__ ea,
    const float* __restrict__ W, const float* __restrict__ b,
    __hip_bfloat16* __restrict__ h1)
{
  int t = blockIdx.x * 256 + threadIdx.x;   // < NE*8 = 480000
  int e = t >> 3, kg = t & 7;
  f32x4 a = *reinterpret_cast<const f32x4*>(ea + e * 4);
  uint ww[8];
#pragma unroll
  for (int p = 0; p < 8; ++p) {
    int k = kg * 16 + p * 2;
    float v0 = b[k]     + dot4(a, *reinterpret_cast<const f32x4*>(W + k * 4));
    float v1 = b[k + 1] + dot4(a, *reinterpret_cast<const f32x4*>(W + (k + 1) * 4));
    ww[p] = (uint)f2bf(fmaxf(v0, 0.f)) | ((uint)f2bf(fmaxf(v1, 0.f)) << 16);
  }
  uint4* dst = reinterpret_cast<uint4*>(h1 + (size_t)e * KH + kg * 16);
  uint4 u0; u0.x = ww[0]; u0.y = ww[1]; u0.z = ww[2]; u0.w = ww[3];
  uint4 u1; u1.x = ww[4]; u1.y = ww[5]; u1.z = ww[6]; u1.w = ww[7];
  dst[0] = u0; dst[1] = u1;
}

// ---------------- degree ----------------
__global__ __launch_bounds__(256) void k_deg(const int* __restrict__ tgt, int* __restrict__ cnt)
{
  int e = blockIdx.x * 256 + threadIdx.x;
  if (e < NE) atomicAdd(&cnt[tgt[e]], 1);
}

// ------------- ONE pack kernel: bpre | WG | PH1 | Lih | Lhh | L1p | inv_deg -------------
// bpre: MFMA B-frag order. WG: [j/4][6][64][4]. PH1: [i/4][2][64][4] (b_h2 | W_root).
// Lih: [j/4][4][64][4]. Lhh: [j/4][4][64][4]. L1p: [j/4][64][4].
__global__ __launch_bounds__(256) void k_pack(const float* __restrict__ W_h2,
    const float* __restrict__ W_ih, const float* __restrict__ W_hh,
    const float* __restrict__ b_h2, const float* __restrict__ W_root,
    const float* __restrict__ W_lih, const float* __restrict__ W_lhh,
    const float* __restrict__ W_lin1, const int* __restrict__ cnt,
    __hip_bfloat16* __restrict__ bpre, float* __restrict__ WG,
    float* __restrict__ PH1, float* __restrict__ Lih, float* __restrict__ Lhh,
    float* __restrict__ L1p, float* __restrict__ inv)
{
  int t = blockIdx.x * 256 + threadIdx.x;
  if (t < 524288) {
    int j = t & 7, l = (t >> 3) & 63, ot = (t >> 9) & 3, ks = (t >> 11) & 3, i = t >> 13;
    int row = i * MD + ot * 16 + (l & 15);
    int col = ks * 32 + (l >> 4) * 8 + j;
    bpre[t] = __float2bfloat16(W_h2[row * KH + col]);
  } else if ((t -= 524288) < 24576) {
    int jb = t / 1536, r = t % 1536;
    int g = r >> 8, r2 = r & 255, d = r2 >> 2, j = jb * 4 + (r2 & 3);
    WG[t] = (g < 3) ? W_ih[(g * 64 + d) * 64 + j] : W_hh[((g - 3) * 64 + d) * 64 + j];
  } else if ((t -= 24576) < 8192) {
    int ib = t >> 9, r = t & 511;
    int which = r >> 8, r2 = r & 255, d = r2 >> 2, i = ib * 4 + (r2 & 3);
    PH1[t] = which ? W_root[i * 64 + d] : b_h2[i * 64 + d];
  } else if ((t -= 8192) < 32768) {
    int jb = t >> 10, r = t & 1023;
    int g = r >> 8, r2 = r & 255, d = r2 >> 2, j = jb * 4 + (r2 & 3);
    Lih[t] = W_lih[(g * 64 + d) * 128 + j];
  } else if ((t -= 32768) < 16384) {
    int jb = t >> 10, r = t & 1023;
    int g = r >> 8, r2 = r & 255, d = r2 >> 2, j = jb * 4 + (r2 & 3);
    Lhh[t] = W_lhh[(g * 64 + d) * 64 + j];
  } else if ((t -= 16384) < 8192) {
    int jb = t >> 8, r = t & 255, d = r >> 2, j = jb * 4 + (r & 3);
    L1p[t] = W_lin1[d * 128 + j];
  } else if ((t -= 8192) < NN) {
    inv[t] = 1.0f / fmaxf((float)cnt[t], 1.0f);
  }
}

// ------------- message kernel: 128 edges/block, 4 waves x 32 edges, i-split x2 ---------
// (R15-proven 89us: i processed in PAIRS, 16 barrier-pairs.) Partial C -> atomic aggr.
__global__ __launch_bounds__(256, 3) void k_msg(
    const __hip_bfloat16* __restrict__ h1,
    const __hip_bfloat16* __restrict__ bpre,
    const float* __restrict__ node_h,
    const int* __restrict__ src,
    const int* __restrict__ tgt,
    float* __restrict__ sx,
    float* __restrict__ aggr)
{
  __shared__ float xT[32 * 132];     // [i-i0][edge], stride 132 (16B-aligned rows)
  __shared__ bf16x8 stage[2048];     // 32KB: 2 i-values x 16 fragments x 64 lanes
  __shared__ int s_src[128];
  __shared__ int s_tgt[128];
  const int tid = threadIdx.x;       // 0..255
  const int wid = tid >> 6;          // 0..3
  const int lane = tid & 63;
  const int eb0 = blockIdx.x * 128;
  const int i0 = blockIdx.y * 32;

  if (tid < 128) {
    int ge = eb0 + tid;
    bool v = ge < NE;
    s_src[tid] = v ? src[ge] : -1;
    s_tgt[tid] = v ? tgt[ge] : -1;
  }
  __syncthreads();
  // stage xT (transposed, this i-range) + fused partial segment-sum of x_src
#pragma unroll 4
  for (int k = 0; k < 16; ++k) {
    int idx = k * 256 + tid;          // < 4096 = 128 edges * 32 dims
    int el = idx >> 5, dd = idx & 31;
    int s = s_src[el];
    float v = (s >= 0) ? node_h[s * MD + i0 + dd] : 0.0f;
    xT[dd * 132 + el] = v;
    if (s >= 0) atomicAdd(&sx[s_tgt[el] * MD + i0 + dd], v);
  }

  // A fragments: h1 rows (edges). lane: row = lane&15, k = ks*32 + (lane>>4)*8 + j
  const int ew = wid * 32;
  bf16x8 af[2][4];
#pragma unroll
  for (int m = 0; m < 2; ++m) {
    int ge = eb0 + ew + m * 16 + (lane & 15);
    if (ge >= NE) ge = 0;                      // xT row is 0 for OOB -> contribution = 0
    const bf16x8* ap = reinterpret_cast<const bf16x8*>(h1 + (size_t)ge * KH);
#pragma unroll
    for (int ks = 0; ks < 4; ++ks)
      af[m][ks] = ap[ks * 4 + (lane >> 4)];
  }

  // prologue: stage fragments for pair 0 (i0, i0+1); wave wid owns frags 4*wid..4*wid+3
  const bf16x8* bpre8 = reinterpret_cast<const bf16x8*>(bpre);
  const int fb = wid << 2;
  {
    bf16x8 r0[8];
#pragma unroll
    for (int q = 0; q < 8; ++q) {
      int p = q >> 2, f = fb + (q & 3);
      r0[q] = bpre8[((((i0 + p) * 16) + f) << 6) + lane];
    }
#pragma unroll
    for (int q = 0; q < 8; ++q) {
      int p = q >> 2, f = fb + (q & 3);
      stage[(p << 10) + (f << 6) + lane] = r0[q];
    }
  }
  __syncthreads();   // xT + stage ready

  const f32x4 z4 = {0.0f, 0.0f, 0.0f, 0.0f};
  f32x4 c[2][4];
#pragma unroll
  for (int m = 0; m < 2; ++m)
#pragma unroll
    for (int ot = 0; ot < 4; ++ot) c[m][ot] = z4;

  for (int i2 = 0; i2 < 16; ++i2) {
    // issue next pair's fragment loads early (in flight across the read phase)
    bf16x8 rn[8];
    if (i2 < 15) {
#pragma unroll
      for (int q = 0; q < 8; ++q) {
        int p = q >> 2, f = fb + (q & 3);
        rn[q] = bpre8[((((i0 + (i2 + 1) * 2 + p) * 16) + f) << 6) + lane];
      }
    }
    // compute both i's of the pair from stage
#pragma unroll
    for (int p = 0; p < 2; ++p) {
      const int ii = i2 * 2 + p;
      f32x4 g[2][4];
#pragma unroll
      for (int ks = 0; ks < 4; ++ks) {
        bf16x8 bfr[4];
#pragma unroll
        for (int ot = 0; ot < 4; ++ot)
          bfr[ot] = stage[(p << 10) + (((ks * 4 + ot)) << 6) + lane];
#pragma unroll
        for (int ot = 0; ot < 4; ++ot)
#pragma unroll
          for (int m = 0; m < 2; ++m)
            g[m][ot] = __builtin_amdgcn_mfma_f32_16x16x32_bf16(
                af[m][ks], bfr[ot], (ks == 0) ? z4 : g[m][ot], 0, 0, 0);
      }
#pragma unroll
      for (int m = 0; m < 2; ++m) {
        f32x4 xv = *reinterpret_cast<const f32x4*>(
            &xT[ii * 132 + ew + m * 16 + ((lane >> 4) << 2)]);
#pragma unroll
        for (int ot = 0; ot < 4; ++ot)
          c[m][ot] += xv * g[m][ot];
      }
    }
    __syncthreads();   // all waves done READING stage for this pair
    if (i2 < 15) {
#pragma unroll
      for (int q = 0; q < 8; ++q) {
        int p = q >> 2, f = fb + (q & 3);
        stage[(p << 10) + (f << 6) + lane] = rn[q];
      }
    }
    __syncthreads();   // stage holds next pair
  }

  // scatter partial C into aggr[tgt]  (C/D layout: col=lane&15, row=(lane>>4)*4+r)
#pragma unroll
  for (int m = 0; m < 2; ++m)
#pragma unroll
    for (int r = 0; r < 4; ++r) {
      int el = ew + m * 16 + (lane >> 4) * 4 + r;
      int t = s_tgt[el];
      if (t >= 0) {
#pragma unroll
        for (int ot = 0; ot < 4; ++ot)
          atomicAdd(&aggr[t * MD + ot * 16 + (lane & 15)], c[m][ot][r]);
      }
    }
}

// ------------- NNConv epilogue + GRU: 16 nodes/block, 2 waves, 8 nodes/thread -------------
// (R10-R15-proven shape.) NEW: zeroes aggr/sx immediately after consuming them, replacing
// the per-step memset launches (same coalesced write pattern, overlapped with compute).
__global__ __launch_bounds__(128) void k_gru(
    float* __restrict__ node_h,
    float* __restrict__ aggr, float* __restrict__ sx,
    const float* __restrict__ inv_deg,
    const f32x4* __restrict__ WG,      // [j/4][6][64] f32x4
    const f32x4* __restrict__ PH1,     // [i/4][2][64] f32x4
    const float* __restrict__ b_conv,
    const float* __restrict__ b_ih, const float* __restrict__ b_hh)
{
  __shared__ float h_s[16][64], sx_s[16][64], m_s[16][64];
  const f32x4 z4 = {0.f, 0.f, 0.f, 0.f};
  int tid = threadIdx.x, w = tid >> 6, d = tid & 63;
  int n0 = blockIdx.x * 16;
  {
    const f32x4* hp = reinterpret_cast<const f32x4*>(node_h + (size_t)n0 * MD);
    f32x4* sp = reinterpret_cast<f32x4*>(sx + (size_t)n0 * MD);
    f32x4* hs4 = reinterpret_cast<f32x4*>(&h_s[0][0]);
    f32x4* ss4 = reinterpret_cast<f32x4*>(&sx_s[0][0]);
#pragma unroll
    for (int k = tid; k < 256; k += 128) {
      bool ok = (n0 + (k >> 4)) < NN;
      hs4[k] = ok ? hp[k] : z4;
      ss4[k] = ok ? sp[k] : z4;
      if (ok) sp[k] = z4;                     // sx consumed -> zero for next step
    }
  }
  __syncthreads();
  const int gb = w * 8;                       // this wave's first node (block-local)
  float acc[8], mr[8];
#pragma unroll
  for (int g = 0; g < 8; ++g) {
    int n = n0 + gb + g;
    acc[g] = (n < NN) ? aggr[n * MD + d] : 0.f;
    if (n < NN) aggr[n * MD + d] = 0.f;       // aggr consumed -> zero for next step
    mr[g] = 0.f;
  }
  for (int ib = 0; ib < 16; ++ib) {
    f32x4 wsx = PH1[ib * 128 + d];
    f32x4 wrt = PH1[ib * 128 + 64 + d];
#pragma unroll
    for (int g = 0; g < 8; ++g) {
      f32x4 s4 = *reinterpret_cast<const f32x4*>(&sx_s[gb + g][ib * 4]);
      f32x4 h4 = *reinterpret_cast<const f32x4*>(&h_s[gb + g][ib * 4]);
      acc[g] += dot4(s4, wsx);
      mr[g]  += dot4(h4, wrt);
    }
  }
  float bc = b_conv[d];
#pragma unroll
  for (int g = 0; g < 8; ++g) {
    int n = n0 + gb + g;
    float iv = (n < NN) ? inv_deg[n] : 1.f;
    m_s[gb + g][d] = fmaxf(acc[g] * iv + mr[g] + bc, 0.f);
  }
  // m_s is wave-local (written and read by the same wave) - no barrier needed
  float gir[8], giz[8], gin[8], ghr[8], ghz[8], ghn[8];
  float bi0 = b_ih[d], bi1 = b_ih[64 + d], bi2 = b_ih[128 + d];
  float bh0 = b_hh[d], bh1 = b_hh[64 + d], bh2 = b_hh[128 + d];
#pragma unroll
  for (int g = 0; g < 8; ++g) {
    gir[g] = bi0; giz[g] = bi1; gin[g] = bi2;
    ghr[g] = bh0; ghz[g] = bh1; ghn[g] = bh2;
  }
  for (int jb = 0; jb < 16; ++jb) {
    f32x4 w0 = WG[jb * 384 + d];
    f32x4 w1 = WG[jb * 384 + 64 + d];
    f32x4 w2 = WG[jb * 384 + 128 + d];
    f32x4 w3 = WG[jb * 384 + 192 + d];
    f32x4 w4 = WG[jb * 384 + 256 + d];
    f32x4 w5 = WG[jb * 384 + 320 + d];
#pragma unroll
    for (int g = 0; g < 8; ++g) {
      f32x4 m4 = *reinterpret_cast<const f32x4*>(&m_s[gb + g][jb * 4]);
      f32x4 h4 = *reinterpret_cast<const f32x4*>(&h_s[gb + g][jb * 4]);
      gir[g] += dot4(m4, w0); giz[g] += dot4(m4, w1); gin[g] += dot4(m4, w2);
      ghr[g] += dot4(h4, w3); ghz[g] += dot4(h4, w4); ghn[g] += dot4(h4, w5);
    }
  }
#pragma unroll
  for (int g = 0; g < 8; ++g) {
    int n = n0 + gb + g;
    if (n < NN) {
      float hv = h_s[gb + g][d];
      float r = sigf(gir[g] + ghr[g]), z = sigf(giz[g] + ghz[g]);
      float nv = tanhf(gin[g] + r * ghn[g]);
      node_h[n * MD + d] = (1.f - z) * nv + z * hv;
    }
  }
}

// ------------- fused Set2Set (3 iters) + head: 256 threads, ONE graph per block ----------
// (R12-proven: gate-row-parallel GEMV + unroll-8 latency batching; state in LDS.)
__global__ __launch_bounds__(256) void k_s2s(const float* __restrict__ node_h,
    const f32x4* __restrict__ Lih, const f32x4* __restrict__ Lhh,
    const float* __restrict__ b_lih, const float* __restrict__ b_lhh,
    const f32x4* __restrict__ L1p, const float* __restrict__ b_lin1,
    const float* __restrict__ W_lin2, const float* __restrict__ b_lin2,
    float* __restrict__ out)
{
  __shared__ __align__(16) float qs[128];   // q_star = [q | rvec]
  __shared__ __align__(16) float hs[64];
  __shared__ float cls[64];
  __shared__ float ga[256];
  __shared__ float ev[32];
  const int tid = threadIdx.x;
  const int b = blockIdx.x;
  const float* nb = node_h + (size_t)b * PG * MD;

  if (tid < 128) {
    qs[tid] = 0.f;
    if (tid < 64) { hs[tid] = 0.f; cls[tid] = 0.f; }
    qs[64 + (tid & 63)] = 0.f;
  }
  __syncthreads();

  for (int it = 0; it < 3; ++it) {
    // ---- gates: thread t = gate row t (i,f,g,o x 64) ----
    float a0 = b_lih[tid] + b_lhh[tid];
    const f32x4* q4 = reinterpret_cast<const f32x4*>(qs);
#pragma unroll 8
    for (int jb = 0; jb < 32; ++jb)
      a0 += dot4(q4[jb], Lih[jb * 256 + tid]);
    const f32x4* h4 = reinterpret_cast<const f32x4*>(hs);
#pragma unroll 8
    for (int jb = 0; jb < 16; ++jb)
      a0 += dot4(h4[jb], Lhh[jb * 256 + tid]);
    ga[tid] = a0;
    __syncthreads();
    // ---- LSTM pointwise (threads 0..63) ----
    if (tid < 64) {
      float ai = ga[tid], af_ = ga[64 + tid], ag = ga[128 + tid], ao = ga[192 + tid];
      float c = sigf(af_) * cls[tid] + sigf(ai) * tanhf(ag);
      float h = sigf(ao) * tanhf(c);
      cls[tid] = c; hs[tid] = h; qs[tid] = h;
    }
    __syncthreads();
    // ---- attention scores: wave wv handles nodes n = wv, wv+4, ... ----
    {
      int wv = tid >> 6, lane = tid & 63;
      float hv = hs[lane];
      for (int n = wv; n < PG; n += 4) {
        float v = nb[n * MD + lane] * hv;
#pragma unroll
        for (int m = 32; m >= 1; m >>= 1) v += __shfl_xor(v, m, 64);
        if (lane == 0) ev[n] = v;
      }
    }
    __syncthreads();
    // ---- softmax + rvec (threads 0..63; ev reads are LDS broadcasts) ----
    if (tid < 64) {
      float emax = -3.0e38f;
#pragma unroll
      for (int n = 0; n < PG; ++n) emax = fmaxf(emax, ev[n]);
      float s = 0.f, rv = 0.f;
#pragma unroll
      for (int n = 0; n < PG; ++n) {
        float w_ = expf(ev[n] - emax);
        s += w_;
        rv += w_ * nb[n * MD + tid];
      }
      qs[64 + tid] = rv / s;
    }
    __syncthreads();
  }
  // ---- head (threads 0..63) ----
  if (tid < 64) {
    const f32x4* q4 = reinterpret_cast<const f32x4*>(qs);
    float aa = b_lin1[tid];
#pragma unroll 8
    for (int jb = 0; jb < 32; ++jb) aa += dot4(q4[jb], L1p[jb * 64 + tid]);
    aa = fmaxf(aa, 0.f);
    float v = aa * W_lin2[tid];
#pragma unroll
    for (int m = 32; m >= 1; m >>= 1) v += __shfl_xor(v, m, 64);
    if (tid == 0) out[b] = v + b_lin2[0];
  }
}

} // namespace

extern "C" void kernel_launch(void* const* d_in, const int* in_sizes, int n_in,
                              void* d_out, int out_size, void* d_ws, size_t ws_size,
                              hipStream_t stream)
{
  const float* x      = (const float*)d_in[0];
  const float* ea     = (const float*)d_in[1];
  const float* W_lin0 = (const float*)d_in[2];
  const float* b_lin0 = (const float*)d_in[3];
  const float* W_h1   = (const float*)d_in[4];
  const float* b_h1   = (const float*)d_in[5];
  const float* W_h2   = (const float*)d_in[6];
  const float* b_h2   = (const float*)d_in[7];
  const float* W_root = (const float*)d_in[8];
  const float* b_conv = (const float*)d_in[9];
  const float* W_ih   = (const float*)d_in[10];
  const float* W_hh   = (const float*)d_in[11];
  const float* b_ih   = (const float*)d_in[12];
  const float* b_hh   = (const float*)d_in[13];
  const float* W_lih  = (const float*)d_in[14];
  const float* W_lhh  = (const float*)d_in[15];
  const float* b_lih  = (const float*)d_in[16];
  const float* b_lhh  = (const float*)d_in[17];
  const float* W_lin1 = (const float*)d_in[18];
  const float* b_lin1 = (const float*)d_in[19];
  const float* W_lin2 = (const float*)d_in[20];
  const float* b_lin2 = (const float*)d_in[21];
  const int*   eidx   = (const int*)d_in[22];
  const int* src = eidx;
  const int* tgt = eidx + NE;
  float* out = (float*)d_out;
  (void)in_sizes; (void)n_in; (void)out_size; (void)ws_size;

  // ---- workspace carve-up (~40 MB) ----
  char* w = (char*)d_ws;
  size_t off = 0;
  auto take = [&](size_t bytes) -> void* {
    void* p = w + off;
    off += (bytes + 255) & ~(size_t)255;
    return p;
  };
  float* node_h        = (float*)take((size_t)NN * MD * 4);
  __hip_bfloat16* h1   = (__hip_bfloat16*)take((size_t)NE * KH * 2);
  __hip_bfloat16* bpre = (__hip_bfloat16*)take((size_t)524288 * 2);
  float* aggr          = (float*)take((size_t)NN * MD * 4);  // aggr, sx contiguous
  float* sx            = (float*)take((size_t)NN * MD * 4);
  float* inv_deg       = (float*)take((size_t)NN * 4);
  int*   deg_cnt       = (int*)take((size_t)NN * 4);
  float* WG            = (float*)take((size_t)24576 * 4);
  float* PH1           = (float*)take((size_t)8192 * 4);
  float* Lih           = (float*)take((size_t)32768 * 4);
  float* Lhh           = (float*)take((size_t)16384 * 4);
  float* L1p           = (float*)take((size_t)8192 * 4);

  hipMemsetAsync(deg_cnt, 0, (size_t)NN * 4, stream);
  // one-time zero of aggr+sx (first-call 0xAA poison); k_gru re-zeroes them each step
  hipMemsetAsync(aggr, 0, (size_t)NN * MD * 4 * 2, stream);
  k_deg<<<(NE + 255) / 256, 256, 0, stream>>>(tgt, deg_cnt);
  k_pack<<<2518, 256, 0, stream>>>(W_h2, W_ih, W_hh, b_h2, W_root, W_lih, W_lhh,
                                   W_lin1, deg_cnt, bpre, WG, PH1, Lih, Lhh, L1p,
                                   inv_deg);
  k_lin0<<<NN / 4, 256, 0, stream>>>(x, W_lin0, b_lin0, node_h);
  k_h1<<<(NE * 8) / 256, 256, 0, stream>>>(ea, W_h1, b_h1, h1);

  dim3 msg_grid((NE + 127) / 128, 2);
  for (int step = 0; step < 3; ++step) {
    k_msg<<<msg_grid, 256, 0, stream>>>(h1, bpre, node_h, src, tgt, sx, aggr);
    k_gru<<<(NN + 15) / 16, 128, 0, stream>>>(node_h, aggr, sx, inv_deg,
                                              (const f32x4*)WG, (const f32x4*)PH1,
                                              b_conv, b_ih, b_hh);
  }

  k_s2s<<<NB, 256, 0, stream>>>(node_h, (const f32x4*)Lih, (const f32x4*)Lhh,
                                b_lih, b_lhh, (const f32x4*)L1p, b_lin1,
                                W_lin2, b_lin2, out);
}